// Round 12
// baseline (40.759 us; speedup 1.0000x reference)
//
#include <hip/hip_runtime.h>

#define EPSF 1e-8f
#define PROB_PENALTYF 1e-4f
#define REV_SCALEF 0.1f
#define INFBITS 0x7F800000u
#define ONEBF ((unsigned short)0x3F80)   // bf16 1.0
#define SENT_C 1.0e6f

#define PTW 4     // point-tiles per wave
#define WPB 4     // waves per block (256 threads)
#define CS 64     // source tiles per chunk (8 groups x 8 tiles)
#define NG 8      // groups per chunk
#define FBLK 256

typedef __attribute__((ext_vector_type(8))) short short8;   // 8 bf16 (4 VGPRs)
typedef __attribute__((ext_vector_type(4))) float f32x4;

__device__ __forceinline__ float min3f(float a, float b, float c) {
    return fminf(fminf(a, b), c);   // -> v_min3_f32
}

// ---- bf16 helpers (RTN split: f = hi + lo to ~2^-17 relative) ----
__device__ __forceinline__ unsigned short bfh(float f) {
    unsigned u = __float_as_uint(f);
    return (unsigned short)((u + 0x7FFFu + ((u >> 16) & 1u)) >> 16);
}
__device__ __forceinline__ float bftof(unsigned short h) {
    return __uint_as_float(((unsigned)h) << 16);
}
__device__ __forceinline__ unsigned short bfl(float f, unsigned short h) {
    return bfh(f - bftof(h));
}
__device__ __forceinline__ unsigned pk(unsigned short lo, unsigned short hi) {
    return (unsigned)lo | ((unsigned)hi << 16);
}

// K-slot packing (A row side holds point P={tx,ty,tz,p2}, t=-2p; B col side
// holds source V={vx,vy,vz,v2}). Sum over k of A[k]*B[k] =
//   k0-2 : t_hi.xyz * v_hi.xyz ; k3-5 : t_lo.xyz * v_hi.xyz
//   k6-8 : t_hi.xyz * v_lo.xyz ; k9-10: 1.0 * v2_hi, v2_lo
//   k11-12: p2_hi,p2_lo * 1.0  ; k13-31: zero (lanes 32-63 hold zero A-frags)
// => D[row][col] = |p|^2 + |v|^2 - 2 p.v  at ~fp32 precision.
__device__ __forceinline__ uint4 makeAfrag(float x, float y, float z, float w, int g) {
    unsigned short hx = bfh(x), hy = bfh(y), hz = bfh(z);
    uint4 r;
    if (g == 0) {
        unsigned short lx = bfl(x, hx), ly = bfl(y, hy), lz = bfl(z, hz);
        r.x = pk(hx, hy); r.y = pk(hz, lx); r.z = pk(ly, lz); r.w = pk(hx, hy);
    } else {
        unsigned short hw = bfh(w), lw = bfl(w, hw);
        r.x = pk(hz, ONEBF); r.y = pk(ONEBF, hw); r.z = pk(lw, 0); r.w = 0u;
    }
    return r;
}
__device__ __forceinline__ uint4 makeBfrag(float x, float y, float z, float w, int g) {
    unsigned short hx = bfh(x), hy = bfh(y), hz = bfh(z);
    uint4 r;
    if (g == 0) {
        unsigned short lx = bfl(x, hx), ly = bfl(y, hy);
        r.x = pk(hx, hy); r.y = pk(hz, hx); r.z = pk(hy, hz); r.w = pk(lx, ly);
    } else {
        unsigned short lz = bfl(z, hz);
        unsigned short hw = bfh(w), lw = bfl(w, hw);
        r.x = pk(lz, hw); r.y = pk(lw, ONEBF); r.z = pk(ONEBF, 0); r.w = 0u;
    }
    return r;
}

// ---------------- kernel 0: prep (build all MFMA fragments + init) ----------------
__global__ void prep_kernel(const float* __restrict__ overts,
                            const int* __restrict__ ofaces,
                            const float* __restrict__ sverts,
                            const int* __restrict__ sfaces,
                            const float* __restrict__ u1,
                            const float* __restrict__ u2,
                            uint4* __restrict__ revA, uint4* __restrict__ fwdA,
                            uint4* __restrict__ revB, uint4* __restrict__ fwdB,
                            unsigned* __restrict__ rev_min,
                            unsigned* __restrict__ fwd_min,
                            float* __restrict__ acc,
                            int n_orig, int f_orig, int fs, int S, int npts,
                            int revPt, int fwdPt, int revSt, int fwdSt) {
    int tid = blockIdx.x * blockDim.x + threadIdx.x;
    const float third = 1.0f / 3.0f;
    int r0 = revPt * 32, r1 = r0 + fwdPt * 32, r2 = r1 + revSt * 32, r3 = r2 + fwdSt * 32;

    if (tid < r0) {
        int l = tid & 31, g = l >> 4;
        int k = (tid >> 5) * 16 + (l & 15);
        float x = 0.f, y = 0.f, z = 0.f;
        if (k < npts) {
            int f = k / S;
            float rr = sqrtf(u1[k]);
            float uu = u2[k];
            float wa = 1.0f - rr, wb = rr * (1.0f - uu), wc = rr * uu;
            int a = sfaces[3 * f], b = sfaces[3 * f + 1], c = sfaces[3 * f + 2];
            x = wa * sverts[3 * a] + wb * sverts[3 * b] + wc * sverts[3 * c];
            y = wa * sverts[3 * a + 1] + wb * sverts[3 * b + 1] + wc * sverts[3 * c + 1];
            z = wa * sverts[3 * a + 2] + wb * sverts[3 * b + 2] + wc * sverts[3 * c + 2];
        }
        float p2 = x * x + y * y + z * z;
        revA[tid] = makeAfrag(-2.f * x, -2.f * y, -2.f * z, p2, g);
    } else if (tid < r1) {
        int t2 = tid - r0;
        int l = t2 & 31, g = l >> 4;
        int k = (t2 >> 5) * 16 + (l & 15);
        float x = 0.f, y = 0.f, z = 0.f;
        if (k < fs) {
            int a = sfaces[3 * k], b = sfaces[3 * k + 1], c = sfaces[3 * k + 2];
            x = (sverts[3 * a] + sverts[3 * b] + sverts[3 * c]) * third;
            y = (sverts[3 * a + 1] + sverts[3 * b + 1] + sverts[3 * c + 1]) * third;
            z = (sverts[3 * a + 2] + sverts[3 * b + 2] + sverts[3 * c + 2]) * third;
        }
        float p2 = x * x + y * y + z * z;
        fwdA[t2] = makeAfrag(-2.f * x, -2.f * y, -2.f * z, p2, g);
    } else if (tid < r2) {
        int t2 = tid - r1;
        int l = t2 & 31, g = l >> 4;
        int s = (t2 >> 5) * 16 + (l & 15);
        float x = SENT_C, y = SENT_C, z = SENT_C;
        if (s < n_orig) { x = overts[3 * s]; y = overts[3 * s + 1]; z = overts[3 * s + 2]; }
        revB[t2] = makeBfrag(x, y, z, x * x + y * y + z * z, g);
    } else if (tid < r3) {
        int t2 = tid - r2;
        int l = t2 & 31, g = l >> 4;
        int s = (t2 >> 5) * 16 + (l & 15);
        float x = SENT_C, y = SENT_C, z = SENT_C;
        if (s < f_orig) {
            int a = ofaces[3 * s], b = ofaces[3 * s + 1], c = ofaces[3 * s + 2];
            x = (overts[3 * a] + overts[3 * b] + overts[3 * c]) * third;
            y = (overts[3 * a + 1] + overts[3 * b + 1] + overts[3 * c + 1]) * third;
            z = (overts[3 * a + 2] + overts[3 * b + 2] + overts[3 * c + 2]) * third;
        }
        fwdB[t2] = makeBfrag(x, y, z, x * x + y * y + z * z, g);
    } else {
        int t2 = tid - r3;
        if (t2 < npts) rev_min[t2] = INFBITS;
        if (t2 < fs)   fwd_min[t2] = INFBITS;
        if (t2 < 8)    acc[t2] = 0.0f;
    }
}

// ---------------- kernel 1: MFMA min-distance, LDS-staged double-buffered B ----------------
// All 4 waves of a block share one source-chunk (group counts padded to %4==0).
// Per group of 8 tiles: issue next group's global loads to regs, compute current
// buffer from LDS (ds_read_b128 + MFMA pairs + v_min3), ds_write next buffer,
// one barrier. Tile-granular index clamp => duplicated REAL tiles (min-safe).
__global__ void __launch_bounds__(256, 4)
mfma_min_kernel(const uint4* __restrict__ revA, const uint4* __restrict__ fwdA,
                const uint4* __restrict__ revB, const uint4* __restrict__ fwdB,
                unsigned* __restrict__ rev_min, unsigned* __restrict__ fwd_min,
                int revGroups, int revWaves, int revPt, int revNpts, int revSt,
                int fwdGroups, int fwdPt, int fwdNpts, int fwdSt) {
    __shared__ short8 lds[2][NG * 32];
    int tid = (int)threadIdx.x;
    int gw = blockIdx.x * WPB + (tid >> 6);
    int lane = tid & 63;

    const uint4 *A, *B;
    unsigned* omin;
    int group, chunk, nTile, npts, nst;
    if (gw < revWaves) {
        A = revA; B = revB; omin = rev_min; nTile = revPt; npts = revNpts; nst = revSt;
        group = gw % revGroups; chunk = gw / revGroups;
    } else {
        int g2 = gw - revWaves;
        A = fwdA; B = fwdB; omin = fwd_min; nTile = fwdPt; npts = fwdNpts; nst = fwdSt;
        group = g2 % fwdGroups; chunk = g2 / fwdGroups;
    }
    int s0 = chunk * CS;

    const short8* A8 = reinterpret_cast<const short8*>(A);
    const short8* B8 = reinterpret_cast<const short8*>(B);

    // ---- A-frags (lanes 0-31 data; lanes 32-63 zero => k16-31 dead) ----
    const short8 zero8 = {0, 0, 0, 0, 0, 0, 0, 0};
    short8 a[PTW];
    int pt0 = group * PTW;
    #pragma unroll
    for (int r = 0; r < PTW; ++r) {
        int ptile = min(pt0 + r, nTile - 1);
        short8 av = A8[(size_t)ptile * 32 + (lane & 31)];
        a[r] = (lane < 32) ? av : zero8;
    }

    float inf = __uint_as_float(INFBITS);
    f32x4 m[PTW];
    #pragma unroll
    for (int r = 0; r < PTW; ++r) m[r] = (f32x4){inf, inf, inf, inf};
    f32x4 cz = {0.f, 0.f, 0.f, 0.f};

    // ---- stage group 0 ----
    {
        int gtile = min(s0 + (tid >> 5), nst - 1);
        lds[0][tid] = B8[(size_t)gtile * 32 + (tid & 31)];
    }
    __syncthreads();

    int cur = 0;
    for (int g = 0; g < NG; ++g) {
        // issue next group's loads early (hide under compute)
        short8 vn;
        if (g + 1 < NG) {
            int gtile = min(s0 + (g + 1) * 8 + (tid >> 5), nst - 1);
            vn = B8[(size_t)gtile * 32 + (tid & 31)];
        }
        // compute 8 tiles in pairs: 2 MFMA + 4 v_min3 per point-tile
        #pragma unroll
        for (int lt = 0; lt < 8; lt += 2) {
            short8 b0 = lds[cur][lt * 32 + (lane & 31)];
            short8 b1 = lds[cur][(lt + 1) * 32 + (lane & 31)];
            #pragma unroll
            for (int r = 0; r < PTW; ++r) {
                f32x4 d0 = __builtin_amdgcn_mfma_f32_16x16x32_bf16(a[r], b0, cz, 0, 0, 0);
                f32x4 d1 = __builtin_amdgcn_mfma_f32_16x16x32_bf16(a[r], b1, cz, 0, 0, 0);
                m[r].x = min3f(m[r].x, d0.x, d1.x);
                m[r].y = min3f(m[r].y, d0.y, d1.y);
                m[r].z = min3f(m[r].z, d0.z, d1.z);
                m[r].w = min3f(m[r].w, d0.w, d1.w);
            }
        }
        if (g + 1 < NG) {
            lds[cur ^ 1][tid] = vn;
        }
        __syncthreads();
        cur ^= 1;
    }

    // min over the 16 cols = min across the 16 lanes of each lane-group
    #pragma unroll
    for (int off = 1; off < 16; off <<= 1) {
        #pragma unroll
        for (int r = 0; r < PTW; ++r) {
            m[r].x = fminf(m[r].x, __shfl_xor(m[r].x, off));
            m[r].y = fminf(m[r].y, __shfl_xor(m[r].y, off));
            m[r].z = fminf(m[r].z, __shfl_xor(m[r].z, off));
            m[r].w = fminf(m[r].w, __shfl_xor(m[r].w, off));
        }
    }

    if ((lane & 15) == 0) {
        int rowbase = (lane >> 4) * 4;   // D row = (lane>>4)*4 + reg
        #pragma unroll
        for (int r = 0; r < PTW; ++r) {
            int pb = min(pt0 + r, nTile - 1) * 16 + rowbase;
            if (pb + 0 < npts) atomicMin(&omin[pb + 0], __float_as_uint(fmaxf(m[r].x, 0.f)));
            if (pb + 1 < npts) atomicMin(&omin[pb + 1], __float_as_uint(fmaxf(m[r].y, 0.f)));
            if (pb + 2 < npts) atomicMin(&omin[pb + 2], __float_as_uint(fmaxf(m[r].z, 0.f)));
            if (pb + 3 < npts) atomicMin(&omin[pb + 3], __float_as_uint(fmaxf(m[r].w, 0.f)));
        }
    }
}

// ---------------- kernel 2: reductions + final scalar (last-block writes out) ----------------
__global__ void finalize_kernel(const unsigned int* __restrict__ fwd_min,
                                const unsigned int* __restrict__ rev_min,
                                const float* __restrict__ fp,
                                float* acc, float* out,
                                int fs, int npts, int S, int nblocks) {
    __shared__ float s1[FBLK], s2[FBLK], s3[FBLK];
    int k = blockIdx.x * blockDim.x + threadIdx.x;
    float fsum = 0.f, rsum = 0.f, rmax = 0.f;
    if (k < npts) {
        float md = __uint_as_float(rev_min[k]);
        float p = fp[k / S];
        rsum = p * md;
        rmax = md;
    }
    if (k < fs) {
        float p = fp[k];
        fsum = p * __uint_as_float(fwd_min[k]) + PROB_PENALTYF * (1.0f - p);
    }
    s1[threadIdx.x] = fsum;
    s2[threadIdx.x] = rsum;
    s3[threadIdx.x] = rmax;
    __syncthreads();
    for (int off = FBLK / 2; off > 0; off >>= 1) {
        if ((int)threadIdx.x < off) {
            s1[threadIdx.x] += s1[threadIdx.x + off];
            s2[threadIdx.x] += s2[threadIdx.x + off];
            s3[threadIdx.x] = fmaxf(s3[threadIdx.x], s3[threadIdx.x + off]);
        }
        __syncthreads();
    }
    if (threadIdx.x == 0) {
        atomicAdd(&acc[0], s1[0]);
        atomicAdd(&acc[1], s2[0]);
        atomicMax((unsigned int*)&acc[2], __float_as_uint(s3[0]));
        __threadfence();
        unsigned int ticket = atomicAdd((unsigned int*)&acc[3], 1u);
        if (ticket == (unsigned int)(nblocks - 1)) {
            __threadfence();
            float a0 = atomicAdd(&acc[0], 0.0f);
            float a1 = atomicAdd(&acc[1], 0.0f);
            unsigned int mb = atomicOr((unsigned int*)&acc[2], 0u);
            out[0] = a0 + a1 * (REV_SCALEF / (__uint_as_float(mb) + EPSF));
        }
    }
}

extern "C" void kernel_launch(void* const* d_in, const int* in_sizes, int n_in,
                              void* d_out, int out_size, void* d_ws, size_t ws_size,
                              hipStream_t stream) {
    const float* overts = (const float*)d_in[0];
    const int*   ofaces = (const int*)d_in[1];
    const float* sverts = (const float*)d_in[2];
    const int*   sfaces = (const int*)d_in[3];
    const float* fp     = (const float*)d_in[4];
    const float* u1     = (const float*)d_in[5];
    const float* u2     = (const float*)d_in[6];
    float* out = (float*)d_out;

    const int N_ORIG = in_sizes[0] / 3;
    const int F_ORIG = in_sizes[1] / 3;
    const int F_SIMP = in_sizes[3] / 3;
    const int S      = in_sizes[5] / F_SIMP;
    const int NPTS   = F_SIMP * S;

    // tile counts (16 points/sources per tile)
    const int revPt = (NPTS + 15) / 16;      // 2000
    const int fwdPt = (F_SIMP + 15) / 16;    // 250
    const int revSt = (N_ORIG + 15) / 16;    // 500
    const int fwdSt = (F_ORIG + 15) / 16;    // 1000

    // workspace: revA | fwdA | revB | fwdB | rev_min | fwd_min | acc
    uint4* revA = (uint4*)d_ws;
    uint4* fwdA = revA + (size_t)revPt * 32;
    uint4* revB = fwdA + (size_t)fwdPt * 32;
    uint4* fwdB = revB + (size_t)revSt * 32;
    unsigned* rev_min = (unsigned*)(fwdB + (size_t)fwdSt * 32);
    unsigned* fwd_min = rev_min + NPTS;
    float* acc = (float*)(fwd_min + F_SIMP);

    // ---- prep ----
    int prepThreads = (revPt + fwdPt + revSt + fwdSt) * 32 + NPTS;
    hipLaunchKernelGGL(prep_kernel, dim3((prepThreads + 255) / 256), dim3(256), 0, stream,
                       overts, ofaces, sverts, sfaces, u1, u2,
                       revA, fwdA, revB, fwdB, rev_min, fwd_min, acc,
                       N_ORIG, F_ORIG, F_SIMP, S, NPTS,
                       revPt, fwdPt, revSt, fwdSt);

    // ---- mfma min ----
    // groups padded to %4==0 so each block's 4 waves share one chunk (barrier-uniform)
    // rev: 500 groups x 8 chunks (64 tiles) = 4000 waves
    // fwd: 64 groups x 16 chunks (64 tiles) = 1024 waves  -> 5024 waves = 1256 blocks
    const int revGroups = (((revPt + PTW - 1) / PTW + 3) & ~3);
    const int revChunks = (revSt + CS - 1) / CS;
    const int revWaves = revGroups * revChunks;

    const int fwdGroups = (((fwdPt + PTW - 1) / PTW + 3) & ~3);
    const int fwdChunks = (fwdSt + CS - 1) / CS;
    const int fwdWaves = fwdGroups * fwdChunks;

    const int totalWaves = revWaves + fwdWaves;   // both %4==0
    const int mblocks = totalWaves / WPB;
    hipLaunchKernelGGL(mfma_min_kernel, dim3(mblocks), dim3(256), 0, stream,
                       revA, fwdA, revB, fwdB, rev_min, fwd_min,
                       revGroups, revWaves, revPt, NPTS, revSt,
                       fwdGroups, fwdPt, F_SIMP, fwdSt);

    // ---- finalize ----
    const int finBlocks = (NPTS + FBLK - 1) / FBLK;
    hipLaunchKernelGGL(finalize_kernel, dim3(finBlocks), dim3(FBLK), 0, stream,
                       fwd_min, rev_min, fp, acc, out, F_SIMP, NPTS, S, finBlocks);
}